// Round 1
// baseline (489.918 us; speedup 1.0000x reference)
//
#include <hip/hip_runtime.h>
#include <hip/hip_bf16.h>

#define L_TOK 3645
#define MP    3712
#define DIMV  3456
#define EDIM  1024

typedef __attribute__((ext_vector_type(8))) short bf8;   // 8 bf16 in 4 VGPRs
typedef __attribute__((ext_vector_type(4))) short s4v;   // 4 bf16
typedef __attribute__((ext_vector_type(4))) float f4;    // MFMA accumulator

__device__ __forceinline__ short f2b(float f) {          // fp32 -> bf16 RNE
  union { float f; unsigned u; } v; v.f = f;
  unsigned r = v.u + 0x7fffu + ((v.u >> 16) & 1u);
  return (short)(r >> 16);
}
__device__ __forceinline__ float b2f(short s) {
  union { unsigned u; float f; } v; v.u = ((unsigned)(unsigned short)s) << 16;
  return v.f;
}
__device__ __forceinline__ void gld16(const void* g, void* l) {
  __builtin_amdgcn_global_load_lds(
      (const __attribute__((address_space(1))) void*)(unsigned long long)g,
      (__attribute__((address_space(3))) void*)(unsigned)(unsigned long long)l,
      16, 0, 0);
}

// ---------------- converts ----------------
__global__ __launch_bounds__(256) void k_cvt(const float* __restrict__ src,
                                             short* __restrict__ dst, int n4) {
  int i = blockIdx.x * 256 + threadIdx.x;
  if (i >= n4) return;
  float4 v = ((const float4*)src)[i];
  s4v o; o[0] = f2b(v.x); o[1] = f2b(v.y); o[2] = f2b(v.z); o[3] = f2b(v.w);
  ((s4v*)dst)[i] = o;
}
__global__ __launch_bounds__(256) void k_cvt_pad(const float* __restrict__ src,
                                                 short* __restrict__ dst, int n4src, int n4tot) {
  int i = blockIdx.x * 256 + threadIdx.x;
  if (i >= n4tot) return;
  s4v o; o[0] = 0; o[1] = 0; o[2] = 0; o[3] = 0;
  if (i < n4src) {
    float4 v = ((const float4*)src)[i];
    o[0] = f2b(v.x); o[1] = f2b(v.y); o[2] = f2b(v.z); o[3] = f2b(v.w);
  }
  ((s4v*)dst)[i] = o;
}

// ---------------- GEMM (NT: C[m][n] = sum_k A[m][k]*B[n][k]) ----------------
#define GM_GELU   0
#define GM_BIAS   1
#define GM_QSCALE 2
#define GM_RESID  3

template<int MODE>
__global__ __launch_bounds__(256)
void k_gemm(const short* __restrict__ A, long sA,
            const short* __restrict__ B, long sB,
            const float* __restrict__ bias0, const float* __restrict__ bias1,
            const float* __restrict__ bias2,
            void* __restrict__ Cout, long sC,
            int N, int K, const float* __restrict__ resid)
{
  __shared__ short As[128 * 32];
  __shared__ short Bs[128 * 32];
  const int tid  = threadIdx.x;
  const int z    = blockIdx.z;
  const int brow = blockIdx.y * 128;
  const int bcol = blockIdx.x * 128;
  const short* Ab = A + (long)z * sA;
  const short* Bb = B + (long)z * sB;
  const float* bias = (z == 0) ? bias0 : (z == 1 ? bias1 : bias2);

  const int wave = tid >> 6, lane = tid & 63;
  const int lg = lane >> 4, lc = lane & 15;
  const int m0 = (wave >> 1) * 64, n0 = (wave & 1) * 64;

  // staging: 512 chunks of 16B per tile; thread t handles chunks t and t+256.
  const int r0 = tid >> 2, seg = tid & 3;   // row, 16B-seg within 64B row
  const int r1 = r0 + 64;
  const int so0 = (seg ^ (r0 & 3)) * 8;     // source XOR -> swizzled LDS layout
  const int so1 = (seg ^ (r1 & 3)) * 8;
  const short* gA0 = Ab + (long)(brow + r0) * K + so0;
  const short* gA1 = Ab + (long)(brow + r1) * K + so1;
  const short* gB0 = Bb + (long)(bcol + r0) * K + so0;
  const short* gB1 = Bb + (long)(bcol + r1) * K + so1;
  short* lA0 = &As[tid * 8];
  short* lA1 = &As[(tid + 256) * 8];
  short* lB0 = &Bs[tid * 8];
  short* lB1 = &Bs[(tid + 256) * 8];

  f4 acc[4][4];
  f4 zero = {0.f, 0.f, 0.f, 0.f};
#pragma unroll
  for (int i = 0; i < 4; ++i)
#pragma unroll
    for (int j = 0; j < 4; ++j) acc[i][j] = zero;

  for (int kt = 0; kt < K; kt += 32) {
    gld16(gA0, lA0); gld16(gA1, lA1);
    gld16(gB0, lB0); gld16(gB1, lB1);
    gA0 += 32; gA1 += 32; gB0 += 32; gB1 += 32;
    __syncthreads();
    bf8 af[4], bfr[4];
#pragma unroll
    for (int mi = 0; mi < 4; ++mi) {
      int r = m0 + mi * 16 + lc;
      af[mi] = *(const bf8*)&As[r * 32 + ((lg ^ (r & 3)) * 8)];
    }
#pragma unroll
    for (int ni = 0; ni < 4; ++ni) {
      int r = n0 + ni * 16 + lc;
      bfr[ni] = *(const bf8*)&Bs[r * 32 + ((lg ^ (r & 3)) * 8)];
    }
#pragma unroll
    for (int mi = 0; mi < 4; ++mi)
#pragma unroll
      for (int ni = 0; ni < 4; ++ni)
        acc[mi][ni] = __builtin_amdgcn_mfma_f32_16x16x32_bf16(af[mi], bfr[ni], acc[mi][ni], 0, 0, 0);
    __syncthreads();
  }

  if (MODE == GM_RESID) {
    float* C = (float*)Cout;
#pragma unroll
    for (int ni = 0; ni < 4; ++ni) {
      int col = bcol + n0 + ni * 16 + lc;
#pragma unroll
      for (int mi = 0; mi < 4; ++mi)
#pragma unroll
        for (int r = 0; r < 4; ++r) {
          int row = brow + m0 + mi * 16 + lg * 4 + r;
          if (row < L_TOK)
            C[(long)row * N + col] = acc[mi][ni][r] + resid[(long)row * N + col];
        }
    }
  } else {
    short* C = (short*)Cout + (long)z * sC;
    const float alpha = (MODE == GM_QSCALE && z == 0) ? 0.08838834764831845f : 1.0f;
#pragma unroll
    for (int ni = 0; ni < 4; ++ni) {
      int col = bcol + n0 + ni * 16 + lc;
      float bv = bias[col];
#pragma unroll
      for (int mi = 0; mi < 4; ++mi)
#pragma unroll
        for (int r = 0; r < 4; ++r) {
          int row = brow + m0 + mi * 16 + lg * 4 + r;
          float v = acc[mi][ni][r] + bv;
          if (MODE == GM_GELU) v = 0.5f * v * (1.f + erff(v * 0.70710678118654752f));
          v *= alpha;
          C[(long)row * EDIM + col] = f2b(v);
        }
    }
  }
}

// ---------------- LayerNorm (one row per block) ----------------
__global__ __launch_bounds__(256)
void k_ln(const short* __restrict__ A, short* __restrict__ Y,
          const float* __restrict__ g0, const float* __restrict__ g1, const float* __restrict__ g2,
          const float* __restrict__ b0, const float* __restrict__ b1, const float* __restrict__ b2)
{
  const int row = blockIdx.x, z = blockIdx.y;
  const float* g = (z == 0) ? g0 : (z == 1 ? g1 : g2);
  const float* b = (z == 0) ? b0 : (z == 1 ? b1 : b2);
  const short* a = A + ((long)z * MP + row) * EDIM;
  short* y = Y + ((long)z * MP + row) * EDIM;
  const int t = threadIdx.x;
  s4v v = *(const s4v*)&a[t * 4];
  float x0 = b2f(v[0]), x1 = b2f(v[1]), x2 = b2f(v[2]), x3 = b2f(v[3]);
  float s = x0 + x1 + x2 + x3;
  float q = x0 * x0 + x1 * x1 + x2 * x2 + x3 * x3;
#pragma unroll
  for (int off = 1; off < 64; off <<= 1) { s += __shfl_xor(s, off); q += __shfl_xor(q, off); }
  __shared__ float rs[4], rq[4];
  if ((t & 63) == 0) { rs[t >> 6] = s; rq[t >> 6] = q; }
  __syncthreads();
  s = rs[0] + rs[1] + rs[2] + rs[3];
  q = rq[0] + rq[1] + rq[2] + rq[3];
  float mean = s * (1.f / 1024.f);
  float var  = q * (1.f / 1024.f) - mean * mean;
  float rstd = rsqrtf(var + 1e-5f);
  s4v o;
#pragma unroll
  for (int j = 0; j < 4; ++j) {
    int col = t * 4 + j;
    o[j] = f2b((b2f(v[j]) - mean) * rstd * g[col] + b[col]);
  }
  *(s4v*)&y[t * 4] = o;
}

// ---------------- V transpose per head: vpT[h][d][kv] ----------------
__global__ __launch_bounds__(256)
void k_vtrans(const short* __restrict__ vp, short* __restrict__ vpT)
{
  const int kb = blockIdx.x * 64, h = blockIdx.y;
  __shared__ short T[64 * 128];   // [kv][d], 16B-units XOR-swizzled by (kv&7)
  const int tid = threadIdx.x;
#pragma unroll
  for (int i = 0; i < 4; ++i) {
    int c = tid + 256 * i;
    int r = c >> 4, x = c & 15;
    bf8 val = *(const bf8*)&vp[(long)(kb + r) * EDIM + h * 128 + x * 8];
    *(bf8*)&T[r * 128 + ((x ^ (r & 7)) * 8)] = val;
  }
  __syncthreads();
#pragma unroll
  for (int i = 0; i < 4; ++i) {
    int c = tid + 256 * i;
    int dr = c >> 3, x = c & 7;
    short tmp[8];
#pragma unroll
    for (int e = 0; e < 8; ++e) {
      int kv = x * 8 + e;
      tmp[e] = T[kv * 128 + (((dr >> 3) ^ (kv & 7)) << 3) + (dr & 7)];
    }
    *(bf8*)&vpT[((long)h * 128 + dr) * MP + kb + x * 8] = *(bf8*)tmp;
  }
}

// ---------------- fused attention (no-max softmax, deferred denominator) ----
__global__ __launch_bounds__(256)
void k_attn(const short* __restrict__ qp, const short* __restrict__ kp,
            const short* __restrict__ vpT, short* __restrict__ o)
{
  const int bx = blockIdx.x;
  const int h = bx & 7, qb = (bx >> 3) * 64;   // h fastest -> one head per XCD
  const int tid = threadIdx.x, wave = tid >> 6, lane = tid & 63;
  const int lg = lane >> 4, lc = lane & 15;
  __shared__ short Ks[64 * 128];   // [kv][d] swizzled
  __shared__ short Vs[128 * 64];   // [d][kv] (V^T) swizzled
  __shared__ short Ps[4][16 * 64]; // per-wave P tile [q][kv] swizzled

  const int qrow = qb + wave * 16 + lc;
  bf8 qf[4];
#pragma unroll
  for (int d4 = 0; d4 < 4; ++d4)
    qf[d4] = *(const bf8*)&qp[(long)qrow * EDIM + h * 128 + d4 * 32 + lg * 8];

  f4 oacc[8];
  f4 zero = {0.f, 0.f, 0.f, 0.f};
#pragma unroll
  for (int dt = 0; dt < 8; ++dt) oacc[dt] = zero;
  float lsum = 0.f;

  for (int kb = 0; kb < L_TOK; kb += 64) {
#pragma unroll
    for (int i = 0; i < 4; ++i) {            // stage K tile (16KB)
      int c = tid + 256 * i; int r = c >> 4, x = c & 15;
      gld16(&kp[(long)(kb + r) * EDIM + h * 128 + (x ^ (r & 7)) * 8], &Ks[c * 8]);
    }
#pragma unroll
    for (int i = 0; i < 4; ++i) {            // stage V^T tile (16KB)
      int c = tid + 256 * i; int dr = c >> 3, x = c & 7;
      gld16(&vpT[((long)h * 128 + dr) * MP + kb + (x ^ (dr & 7)) * 8], &Vs[c * 8]);
    }
    __syncthreads();

#pragma unroll
    for (int s = 0; s < 4; ++s) {            // S^T = K·Q^T (lane owns column q)
      f4 sa = zero;
      const int krow = s * 16 + lc;
#pragma unroll
      for (int d4 = 0; d4 < 4; ++d4) {
        bf8 kf = *(const bf8*)&Ks[krow * 128 + (((d4 * 4 + lg) ^ (krow & 7)) * 8)];
        sa = __builtin_amdgcn_mfma_f32_16x16x32_bf16(kf, qf[d4], sa, 0, 0, 0);
      }
      const int kvb = kb + s * 16 + lg * 4;
      float p[4];
#pragma unroll
      for (int r = 0; r < 4; ++r) {
        float e = __expf(sa[r]);
        p[r] = (kvb + r < L_TOK) ? e : 0.f;
        lsum += p[r];
      }
      s4v pk; pk[0] = f2b(p[0]); pk[1] = f2b(p[1]); pk[2] = f2b(p[2]); pk[3] = f2b(p[3]);
      *(s4v*)&Ps[wave][lc * 64 + ((s * 16 + lg * 4) ^ ((lc & 7) << 3))] = pk;
    }
    bf8 pf0 = *(const bf8*)&Ps[wave][lc * 64 + ((lg * 8) ^ ((lc & 7) << 3))];
    bf8 pf1 = *(const bf8*)&Ps[wave][lc * 64 + ((32 + lg * 8) ^ ((lc & 7) << 3))];
#pragma unroll
    for (int dt = 0; dt < 8; ++dt) {         // O += P·V
      const int vrow = dt * 16 + lc;
      bf8 vf0 = *(const bf8*)&Vs[vrow * 64 + ((lg ^ (vrow & 7)) * 8)];
      bf8 vf1 = *(const bf8*)&Vs[vrow * 64 + (((4 + lg) ^ (vrow & 7)) * 8)];
      oacc[dt] = __builtin_amdgcn_mfma_f32_16x16x32_bf16(pf0, vf0, oacc[dt], 0, 0, 0);
      oacc[dt] = __builtin_amdgcn_mfma_f32_16x16x32_bf16(pf1, vf1, oacc[dt], 0, 0, 0);
    }
    __syncthreads();
  }

  lsum += __shfl_xor(lsum, 16);              // combine the 4 lane-groups
  lsum += __shfl_xor(lsum, 32);
  float rinv[4];
#pragma unroll
  for (int r = 0; r < 4; ++r) rinv[r] = 1.f / __shfl(lsum, lg * 4 + r);
#pragma unroll
  for (int dt = 0; dt < 8; ++dt)
#pragma unroll
    for (int r = 0; r < 4; ++r) {
      int orow = qb + wave * 16 + lg * 4 + r;
      o[(long)orow * EDIM + h * 128 + dt * 16 + lc] = f2b(oacc[dt][r] * rinv[r]);
    }
}

// ---------------- launch ----------------
extern "C" void kernel_launch(void* const* d_in, const int* in_sizes, int n_in,
                              void* d_out, int out_size, void* d_ws, size_t ws_size,
                              hipStream_t stream)
{
  const float* x   = (const float*)d_in[0];
  const float* ipb = (const float*)d_in[20];
  const float* opb = (const float*)d_in[22];

  char* ws = (char*)d_ws;
  short* regA = (short*)(ws + 0);                  // 25,657,344 B : xb -> aln -> proj
  short* regB = (short*)(ws + 25657344);           // 22,806,528 B : h1 -> lnq -> {o, o2}
  short* w1b  = (short*)(ws + 48463872);
  short* w2b  = (short*)(ws + 69697536);
  short* wpb  = (short*)(ws + 75988992);
  short* wob  = (short*)(ws + 82280448);
  short* wtb  = (short*)(ws + 84377600);
  short* vpT  = (short*)(ws + 91455488);           // end 99,057,664

  short* xb  = regA;
  short* h1  = regB;
  short* aln = regA;
  short* lnq = regB;
  short* proj = regA;
  short* ob  = regB;
  short* o2  = (short*)(ws + 25657344 + 7602176);

  // bf16 conversions
  k_cvt_pad<<<12528, 256, 0, stream>>>(x, xb, 3149280, 3207168);
  k_cvt<<<3456, 256, 0, stream>>>((const float*)d_in[1],  w1b,            884736);
  k_cvt<<<3456, 256, 0, stream>>>((const float*)d_in[7],  w1b + 3538944,  884736);
  k_cvt<<<3456, 256, 0, stream>>>((const float*)d_in[13], w1b + 7077888,  884736);
  k_cvt<<<1024, 256, 0, stream>>>((const float*)d_in[3],  w2b,            262144);
  k_cvt<<<1024, 256, 0, stream>>>((const float*)d_in[9],  w2b + 1048576,  262144);
  k_cvt<<<1024, 256, 0, stream>>>((const float*)d_in[15], w2b + 2097152,  262144);
  k_cvt<<<3072, 256, 0, stream>>>((const float*)d_in[19], wpb,            786432);
  k_cvt<<<1024, 256, 0, stream>>>((const float*)d_in[21], wob,            262144);
  k_cvt<<<3456, 256, 0, stream>>>((const float*)d_in[23], wtb,            884736);

  dim3 g3(8, 29, 3), g1(8, 29, 1);
  // MLP first linear + GELU
  k_gemm<GM_GELU><<<g3, 256, 0, stream>>>(xb, 0, w1b, 3538944,
      (const float*)d_in[2], (const float*)d_in[8], (const float*)d_in[14],
      h1, (long)MP * EDIM, EDIM, DIMV, nullptr);
  // MLP second linear + bias
  k_gemm<GM_BIAS><<<g3, 256, 0, stream>>>(h1, (long)MP * EDIM, w2b, 1048576,
      (const float*)d_in[4], (const float*)d_in[10], (const float*)d_in[16],
      aln, (long)MP * EDIM, EDIM, EDIM, nullptr);
  // LayerNorm
  dim3 gl(MP, 3);
  k_ln<<<gl, 256, 0, stream>>>(aln, lnq,
      (const float*)d_in[5], (const float*)d_in[11], (const float*)d_in[17],
      (const float*)d_in[6], (const float*)d_in[12], (const float*)d_in[18]);
  // in_proj (q scaled by 1/sqrt(D))
  k_gemm<GM_QSCALE><<<g3, 256, 0, stream>>>(lnq, (long)MP * EDIM, wpb, 1048576,
      ipb, ipb + 1024, ipb + 2048,
      proj, (long)MP * EDIM, EDIM, EDIM, nullptr);
  // V transpose per head
  dim3 gt(MP / 64, 8);
  k_vtrans<<<gt, 256, 0, stream>>>(proj + 2L * MP * EDIM, vpT);
  // attention
  k_attn<<<(MP / 64) * 8, 256, 0, stream>>>(proj, proj + (long)MP * EDIM, vpT, ob);
  // out_proj
  k_gemm<GM_BIAS><<<g1, 256, 0, stream>>>(ob, 0, wob, 0,
      opb, opb, opb, o2, 0, EDIM, EDIM, nullptr);
  // to_out + residual (fp32 out)
  dim3 g5(27, 29, 1);
  k_gemm<GM_RESID><<<g5, 256, 0, stream>>>(o2, 0, wtb, 0,
      nullptr, nullptr, nullptr, d_out, 0, DIMV, EDIM, x);
}

// Round 2
// 486.278 us; speedup vs baseline: 1.0075x; 1.0075x over previous
//
#include <hip/hip_runtime.h>
#include <hip/hip_bf16.h>

#define L_TOK 3645
#define MP    3712
#define DIMV  3456
#define EDIM  1024

typedef __attribute__((ext_vector_type(8))) short bf8;   // 8 bf16 in 4 VGPRs
typedef __attribute__((ext_vector_type(4))) short s4v;   // 4 bf16
typedef __attribute__((ext_vector_type(4))) float f4;    // MFMA accumulator

__device__ __forceinline__ short f2b(float f) {          // fp32 -> bf16 RNE
  union { float f; unsigned u; } v; v.f = f;
  unsigned r = v.u + 0x7fffu + ((v.u >> 16) & 1u);
  return (short)(r >> 16);
}
__device__ __forceinline__ float b2f(short s) {
  union { unsigned u; float f; } v; v.u = ((unsigned)(unsigned short)s) << 16;
  return v.f;
}
__device__ __forceinline__ void gld16(const void* g, void* l) {
  __builtin_amdgcn_global_load_lds(
      (const __attribute__((address_space(1))) void*)(unsigned long long)g,
      (__attribute__((address_space(3))) void*)(unsigned)(unsigned long long)l,
      16, 0, 0);
}

// ---------------- converts ----------------
__global__ __launch_bounds__(256) void k_cvt(const float* __restrict__ src,
                                             short* __restrict__ dst, int n4) {
  int i = blockIdx.x * 256 + threadIdx.x;
  if (i >= n4) return;
  float4 v = ((const float4*)src)[i];
  s4v o; o[0] = f2b(v.x); o[1] = f2b(v.y); o[2] = f2b(v.z); o[3] = f2b(v.w);
  ((s4v*)dst)[i] = o;
}
__global__ __launch_bounds__(256) void k_cvt_pad(const float* __restrict__ src,
                                                 short* __restrict__ dst, int n4src, int n4tot) {
  int i = blockIdx.x * 256 + threadIdx.x;
  if (i >= n4tot) return;
  s4v o; o[0] = 0; o[1] = 0; o[2] = 0; o[3] = 0;
  if (i < n4src) {
    float4 v = ((const float4*)src)[i];
    o[0] = f2b(v.x); o[1] = f2b(v.y); o[2] = f2b(v.z); o[3] = f2b(v.w);
  }
  ((s4v*)dst)[i] = o;
}

// ---------------- GEMM (NT: C[m][n] = sum_k A[m][k]*B[n][k]) ----------------
#define GM_GELU   0
#define GM_BIAS   1
#define GM_QSCALE 2
#define GM_RESID  3

template<int MODE>
__global__ __launch_bounds__(256)
void k_gemm(const short* __restrict__ A, long sA,
            const short* __restrict__ B, long sB,
            const float* __restrict__ bias0, const float* __restrict__ bias1,
            const float* __restrict__ bias2,
            void* __restrict__ Cout, long sC,
            int N, int K, const float* __restrict__ resid)
{
  __shared__ short As[128 * 32];
  __shared__ short Bs[128 * 32];
  const int tid  = threadIdx.x;
  const int z    = blockIdx.z;
  const int brow = blockIdx.y * 128;
  const int bcol = blockIdx.x * 128;
  const short* Ab = A + (long)z * sA;
  const short* Bb = B + (long)z * sB;
  const float* bias = (z == 0) ? bias0 : (z == 1 ? bias1 : bias2);

  const int wave = tid >> 6, lane = tid & 63;
  const int lg = lane >> 4, lc = lane & 15;
  const int m0 = (wave >> 1) * 64, n0 = (wave & 1) * 64;

  // staging: 512 chunks of 16B per tile; thread t handles chunks t and t+256.
  // XOR index is (row>>1)&3: rows are 64B, so residue mod 128B = (r&1)*64 +
  // seg*16; XOR by (r>>1)&3 makes each 8-lane service group hit 8 distinct
  // 16B residues -> conflict-free ds_read_b128.
  const int r0 = tid >> 2, seg = tid & 3;   // row, 16B-seg within 64B row
  const int r1 = r0 + 64;
  const int so0 = (seg ^ ((r0 >> 1) & 3)) * 8;  // source XOR -> swizzled LDS
  const int so1 = (seg ^ ((r1 >> 1) & 3)) * 8;
  const short* gA0 = Ab + (long)(brow + r0) * K + so0;
  const short* gA1 = Ab + (long)(brow + r1) * K + so1;
  const short* gB0 = Bb + (long)(bcol + r0) * K + so0;
  const short* gB1 = Bb + (long)(bcol + r1) * K + so1;
  short* lA0 = &As[tid * 8];
  short* lA1 = &As[(tid + 256) * 8];
  short* lB0 = &Bs[tid * 8];
  short* lB1 = &Bs[(tid + 256) * 8];

  f4 acc[4][4];
  f4 zero = {0.f, 0.f, 0.f, 0.f};
#pragma unroll
  for (int i = 0; i < 4; ++i)
#pragma unroll
    for (int j = 0; j < 4; ++j) acc[i][j] = zero;

  for (int kt = 0; kt < K; kt += 32) {
    gld16(gA0, lA0); gld16(gA1, lA1);
    gld16(gB0, lB0); gld16(gB1, lB1);
    gA0 += 32; gA1 += 32; gB0 += 32; gB1 += 32;
    __syncthreads();
    bf8 af[4], bfr[4];
#pragma unroll
    for (int mi = 0; mi < 4; ++mi) {
      int r = m0 + mi * 16 + lc;
      af[mi] = *(const bf8*)&As[r * 32 + ((lg ^ ((r >> 1) & 3)) * 8)];
    }
#pragma unroll
    for (int ni = 0; ni < 4; ++ni) {
      int r = n0 + ni * 16 + lc;
      bfr[ni] = *(const bf8*)&Bs[r * 32 + ((lg ^ ((r >> 1) & 3)) * 8)];
    }
#pragma unroll
    for (int mi = 0; mi < 4; ++mi)
#pragma unroll
      for (int ni = 0; ni < 4; ++ni)
        acc[mi][ni] = __builtin_amdgcn_mfma_f32_16x16x32_bf16(af[mi], bfr[ni], acc[mi][ni], 0, 0, 0);
    __syncthreads();
  }

  if (MODE == GM_RESID) {
    float* C = (float*)Cout;
#pragma unroll
    for (int ni = 0; ni < 4; ++ni) {
      int col = bcol + n0 + ni * 16 + lc;
#pragma unroll
      for (int mi = 0; mi < 4; ++mi)
#pragma unroll
        for (int r = 0; r < 4; ++r) {
          int row = brow + m0 + mi * 16 + lg * 4 + r;
          if (row < L_TOK)
            C[(long)row * N + col] = acc[mi][ni][r] + resid[(long)row * N + col];
        }
    }
  } else {
    short* C = (short*)Cout + (long)z * sC;
    const float alpha = (MODE == GM_QSCALE && z == 0) ? 0.08838834764831845f : 1.0f;
#pragma unroll
    for (int ni = 0; ni < 4; ++ni) {
      int col = bcol + n0 + ni * 16 + lc;
      float bv = bias[col];
#pragma unroll
      for (int mi = 0; mi < 4; ++mi)
#pragma unroll
        for (int r = 0; r < 4; ++r) {
          int row = brow + m0 + mi * 16 + lg * 4 + r;
          float v = acc[mi][ni][r] + bv;
          if (MODE == GM_GELU) v = 0.5f * v * (1.f + erff(v * 0.70710678118654752f));
          v *= alpha;
          C[(long)row * EDIM + col] = f2b(v);
        }
    }
  }
}

// ---------------- LayerNorm (one row per block) ----------------
__global__ __launch_bounds__(256)
void k_ln(const short* __restrict__ A, short* __restrict__ Y,
          const float* __restrict__ g0, const float* __restrict__ g1, const float* __restrict__ g2,
          const float* __restrict__ b0, const float* __restrict__ b1, const float* __restrict__ b2)
{
  const int row = blockIdx.x, z = blockIdx.y;
  const float* g = (z == 0) ? g0 : (z == 1 ? g1 : g2);
  const float* b = (z == 0) ? b0 : (z == 1 ? b1 : b2);
  const short* a = A + ((long)z * MP + row) * EDIM;
  short* y = Y + ((long)z * MP + row) * EDIM;
  const int t = threadIdx.x;
  s4v v = *(const s4v*)&a[t * 4];
  float x0 = b2f(v[0]), x1 = b2f(v[1]), x2 = b2f(v[2]), x3 = b2f(v[3]);
  float s = x0 + x1 + x2 + x3;
  float q = x0 * x0 + x1 * x1 + x2 * x2 + x3 * x3;
#pragma unroll
  for (int off = 1; off < 64; off <<= 1) { s += __shfl_xor(s, off); q += __shfl_xor(q, off); }
  __shared__ float rs[4], rq[4];
  if ((t & 63) == 0) { rs[t >> 6] = s; rq[t >> 6] = q; }
  __syncthreads();
  s = rs[0] + rs[1] + rs[2] + rs[3];
  q = rq[0] + rq[1] + rq[2] + rq[3];
  float mean = s * (1.f / 1024.f);
  float var  = q * (1.f / 1024.f) - mean * mean;
  float rstd = rsqrtf(var + 1e-5f);
  s4v o;
#pragma unroll
  for (int j = 0; j < 4; ++j) {
    int col = t * 4 + j;
    o[j] = f2b((b2f(v[j]) - mean) * rstd * g[col] + b[col]);
  }
  *(s4v*)&y[t * 4] = o;
}

// ---------------- V transpose per head: vpT[h][d][kv] ----------------
__global__ __launch_bounds__(256)
void k_vtrans(const short* __restrict__ vp, short* __restrict__ vpT)
{
  const int kb = blockIdx.x * 64, h = blockIdx.y;
  __shared__ short T[64 * 128];   // [kv][d], 16B-units XOR-swizzled by (kv&7)
  const int tid = threadIdx.x;
#pragma unroll
  for (int i = 0; i < 4; ++i) {
    int c = tid + 256 * i;
    int r = c >> 4, x = c & 15;
    bf8 val = *(const bf8*)&vp[(long)(kb + r) * EDIM + h * 128 + x * 8];
    *(bf8*)&T[r * 128 + ((x ^ (r & 7)) * 8)] = val;
  }
  __syncthreads();
#pragma unroll
  for (int i = 0; i < 4; ++i) {
    int c = tid + 256 * i;
    int dr = c >> 3, x = c & 7;
    short tmp[8];
#pragma unroll
    for (int e = 0; e < 8; ++e) {
      int kv = x * 8 + e;
      tmp[e] = T[kv * 128 + (((dr >> 3) ^ (kv & 7)) << 3) + (dr & 7)];
    }
    *(bf8*)&vpT[((long)h * 128 + dr) * MP + kb + x * 8] = *(bf8*)tmp;
  }
}

// ---------------- fused attention (no-max softmax, deferred denominator) ----
__global__ __launch_bounds__(256)
void k_attn(const short* __restrict__ qp, const short* __restrict__ kp,
            const short* __restrict__ vpT, short* __restrict__ o)
{
  const int bx = blockIdx.x;
  const int h = bx & 7, qb = (bx >> 3) * 64;   // h fastest -> one head per XCD
  const int tid = threadIdx.x, wave = tid >> 6, lane = tid & 63;
  const int lg = lane >> 4, lc = lane & 15;
  __shared__ short Ks[64 * 128];   // [kv][d] swizzled
  __shared__ short Vs[128 * 64];   // [d][kv] (V^T) swizzled
  __shared__ short Ps[4][16 * 64]; // per-wave P tile [q][kv] swizzled

  const int qrow = qb + wave * 16 + lc;
  bf8 qf[4];
#pragma unroll
  for (int d4 = 0; d4 < 4; ++d4)
    qf[d4] = *(const bf8*)&qp[(long)qrow * EDIM + h * 128 + d4 * 32 + lg * 8];

  f4 oacc[8];
  f4 zero = {0.f, 0.f, 0.f, 0.f};
#pragma unroll
  for (int dt = 0; dt < 8; ++dt) oacc[dt] = zero;
  float lsum = 0.f;

  for (int kb = 0; kb < L_TOK; kb += 64) {
#pragma unroll
    for (int i = 0; i < 4; ++i) {            // stage K tile (16KB)
      int c = tid + 256 * i; int r = c >> 4, x = c & 15;
      gld16(&kp[(long)(kb + r) * EDIM + h * 128 + (x ^ (r & 7)) * 8], &Ks[c * 8]);
    }
#pragma unroll
    for (int i = 0; i < 4; ++i) {            // stage V^T tile (16KB)
      int c = tid + 256 * i; int dr = c >> 3, x = c & 7;
      gld16(&vpT[((long)h * 128 + dr) * MP + kb + (x ^ (dr & 7)) * 8], &Vs[c * 8]);
    }
    __syncthreads();

#pragma unroll
    for (int s = 0; s < 4; ++s) {            // S^T = K·Q^T (lane owns column q)
      f4 sa = zero;
      const int krow = s * 16 + lc;
#pragma unroll
      for (int d4 = 0; d4 < 4; ++d4) {
        bf8 kf = *(const bf8*)&Ks[krow * 128 + (((d4 * 4 + lg) ^ (krow & 7)) * 8)];
        sa = __builtin_amdgcn_mfma_f32_16x16x32_bf16(kf, qf[d4], sa, 0, 0, 0);
      }
      const int kvb = kb + s * 16 + lg * 4;
      float p[4];
#pragma unroll
      for (int r = 0; r < 4; ++r) {
        float e = __expf(sa[r]);
        p[r] = (kvb + r < L_TOK) ? e : 0.f;
        lsum += p[r];
      }
      s4v pk; pk[0] = f2b(p[0]); pk[1] = f2b(p[1]); pk[2] = f2b(p[2]); pk[3] = f2b(p[3]);
      *(s4v*)&Ps[wave][lc * 64 + ((s * 16 + lg * 4) ^ ((lc & 7) << 3))] = pk;
    }
    bf8 pf0 = *(const bf8*)&Ps[wave][lc * 64 + ((lg * 8) ^ ((lc & 7) << 3))];
    bf8 pf1 = *(const bf8*)&Ps[wave][lc * 64 + ((32 + lg * 8) ^ ((lc & 7) << 3))];
#pragma unroll
    for (int dt = 0; dt < 8; ++dt) {         // O += P·V
      const int vrow = dt * 16 + lc;
      bf8 vf0 = *(const bf8*)&Vs[vrow * 64 + ((lg ^ (vrow & 7)) * 8)];
      bf8 vf1 = *(const bf8*)&Vs[vrow * 64 + (((4 + lg) ^ (vrow & 7)) * 8)];
      oacc[dt] = __builtin_amdgcn_mfma_f32_16x16x32_bf16(pf0, vf0, oacc[dt], 0, 0, 0);
      oacc[dt] = __builtin_amdgcn_mfma_f32_16x16x32_bf16(pf1, vf1, oacc[dt], 0, 0, 0);
    }
    __syncthreads();
  }

  lsum += __shfl_xor(lsum, 16);              // combine the 4 lane-groups
  lsum += __shfl_xor(lsum, 32);
  float rinv[4];
#pragma unroll
  for (int r = 0; r < 4; ++r) rinv[r] = 1.f / __shfl(lsum, lg * 4 + r);
#pragma unroll
  for (int dt = 0; dt < 8; ++dt)
#pragma unroll
    for (int r = 0; r < 4; ++r) {
      int orow = qb + wave * 16 + lg * 4 + r;
      o[(long)orow * EDIM + h * 128 + dt * 16 + lc] = f2b(oacc[dt][r] * rinv[r]);
    }
}

// ---------------- launch ----------------
extern "C" void kernel_launch(void* const* d_in, const int* in_sizes, int n_in,
                              void* d_out, int out_size, void* d_ws, size_t ws_size,
                              hipStream_t stream)
{
  const float* x   = (const float*)d_in[0];
  const float* ipb = (const float*)d_in[20];
  const float* opb = (const float*)d_in[22];

  char* ws = (char*)d_ws;
  short* regA = (short*)(ws + 0);                  // 25,657,344 B : xb -> aln -> proj
  short* regB = (short*)(ws + 25657344);           // 22,806,528 B : h1 -> lnq -> {o, o2}
  short* w1b  = (short*)(ws + 48463872);
  short* w2b  = (short*)(ws + 69697536);
  short* wpb  = (short*)(ws + 75988992);
  short* wob  = (short*)(ws + 82280448);
  short* wtb  = (short*)(ws + 84377600);
  short* vpT  = (short*)(ws + 91455488);           // end 99,057,664

  short* xb  = regA;
  short* h1  = regB;
  short* aln = regA;
  short* lnq = regB;
  short* proj = regA;
  short* ob  = regB;
  short* o2  = (short*)(ws + 25657344 + 7602176);

  // bf16 conversions
  k_cvt_pad<<<12528, 256, 0, stream>>>(x, xb, 3149280, 3207168);
  k_cvt<<<3456, 256, 0, stream>>>((const float*)d_in[1],  w1b,            884736);
  k_cvt<<<3456, 256, 0, stream>>>((const float*)d_in[7],  w1b + 3538944,  884736);
  k_cvt<<<3456, 256, 0, stream>>>((const float*)d_in[13], w1b + 7077888,  884736);
  k_cvt<<<1024, 256, 0, stream>>>((const float*)d_in[3],  w2b,            262144);
  k_cvt<<<1024, 256, 0, stream>>>((const float*)d_in[9],  w2b + 1048576,  262144);
  k_cvt<<<1024, 256, 0, stream>>>((const float*)d_in[15], w2b + 2097152,  262144);
  k_cvt<<<3072, 256, 0, stream>>>((const float*)d_in[19], wpb,            786432);
  k_cvt<<<1024, 256, 0, stream>>>((const float*)d_in[21], wob,            262144);
  k_cvt<<<3456, 256, 0, stream>>>((const float*)d_in[23], wtb,            884736);

  dim3 g3(8, 29, 3), g1(8, 29, 1);
  // MLP first linear + GELU
  k_gemm<GM_GELU><<<g3, 256, 0, stream>>>(xb, 0, w1b, 3538944,
      (const float*)d_in[2], (const float*)d_in[8], (const float*)d_in[14],
      h1, (long)MP * EDIM, EDIM, DIMV, nullptr);
  // MLP second linear + bias
  k_gemm<GM_BIAS><<<g3, 256, 0, stream>>>(h1, (long)MP * EDIM, w2b, 1048576,
      (const float*)d_in[4], (const float*)d_in[10], (const float*)d_in[16],
      aln, (long)MP * EDIM, EDIM, EDIM, nullptr);
  // LayerNorm
  dim3 gl(MP, 3);
  k_ln<<<gl, 256, 0, stream>>>(aln, lnq,
      (const float*)d_in[5], (const float*)d_in[11], (const float*)d_in[17],
      (const float*)d_in[6], (const float*)d_in[12], (const float*)d_in[18]);
  // in_proj (q scaled by 1/sqrt(D))
  k_gemm<GM_QSCALE><<<g3, 256, 0, stream>>>(lnq, (long)MP * EDIM, wpb, 1048576,
      ipb, ipb + 1024, ipb + 2048,
      proj, (long)MP * EDIM, EDIM, EDIM, nullptr);
  // V transpose per head
  dim3 gt(MP / 64, 8);
  k_vtrans<<<gt, 256, 0, stream>>>(proj + 2L * MP * EDIM, vpT);
  // attention
  k_attn<<<(MP / 64) * 8, 256, 0, stream>>>(proj, proj + (long)MP * EDIM, vpT, ob);
  // out_proj
  k_gemm<GM_BIAS><<<g1, 256, 0, stream>>>(ob, 0, wob, 0,
      opb, opb, opb, o2, 0, EDIM, EDIM, nullptr);
  // to_out + residual (fp32 out)
  dim3 g5(27, 29, 1);
  k_gemm<GM_RESID><<<g5, 256, 0, stream>>>(o2, 0, wtb, 0,
      nullptr, nullptr, nullptr, d_out, 0, DIMV, EDIM, x);
}

// Round 3
// 444.678 us; speedup vs baseline: 1.1017x; 1.0936x over previous
//
#include <hip/hip_runtime.h>
#include <hip/hip_bf16.h>

#define L_TOK 3645
#define MP    3712
#define DIMV  3456
#define EDIM  1024

typedef __attribute__((ext_vector_type(8))) short bf8;   // 8 bf16 in 4 VGPRs
typedef __attribute__((ext_vector_type(4))) short s4v;   // 4 bf16
typedef __attribute__((ext_vector_type(4))) float f4;    // MFMA accumulator

__device__ __forceinline__ short f2b(float f) {          // fp32 -> bf16 RNE
  union { float f; unsigned u; } v; v.f = f;
  unsigned r = v.u + 0x7fffu + ((v.u >> 16) & 1u);
  return (short)(r >> 16);
}
__device__ __forceinline__ float b2f(short s) {
  union { unsigned u; float f; } v; v.u = ((unsigned)(unsigned short)s) << 16;
  return v.f;
}
__device__ __forceinline__ void gld16(const void* g, void* l) {
  __builtin_amdgcn_global_load_lds(
      (const __attribute__((address_space(1))) void*)(unsigned long long)g,
      (__attribute__((address_space(3))) void*)(unsigned)(unsigned long long)l,
      16, 0, 0);
}

// ---------------- converts ----------------
__global__ __launch_bounds__(256) void k_cvt(const float* __restrict__ src,
                                             short* __restrict__ dst, int n4) {
  int i = blockIdx.x * 256 + threadIdx.x;
  if (i >= n4) return;
  float4 v = ((const float4*)src)[i];
  s4v o; o[0] = f2b(v.x); o[1] = f2b(v.y); o[2] = f2b(v.z); o[3] = f2b(v.w);
  ((s4v*)dst)[i] = o;
}
__global__ __launch_bounds__(256) void k_cvt_pad(const float* __restrict__ src,
                                                 short* __restrict__ dst, int n4src, int n4tot) {
  int i = blockIdx.x * 256 + threadIdx.x;
  if (i >= n4tot) return;
  s4v o; o[0] = 0; o[1] = 0; o[2] = 0; o[3] = 0;
  if (i < n4src) {
    float4 v = ((const float4*)src)[i];
    o[0] = f2b(v.x); o[1] = f2b(v.y); o[2] = f2b(v.z); o[3] = f2b(v.w);
  }
  ((s4v*)dst)[i] = o;
}

// ---------------- GEMM (NT: C[m][n] = sum_k A[m][k]*B[n][k]) ----------------
// Triple-buffered LDS, counted vmcnt (never 0 until the last tile), single
// barrier per K-step. Tile t staged 2 iterations ahead of consumption.
#define GM_GELU   0
#define GM_BIAS   1
#define GM_QSCALE 2
#define GM_RESID  3

template<int MODE>
__global__ __launch_bounds__(256)
void k_gemm(const short* __restrict__ A, long sA,
            const short* __restrict__ B, long sB,
            const float* __restrict__ bias0, const float* __restrict__ bias1,
            const float* __restrict__ bias2,
            void* __restrict__ Cout, long sC,
            int N, int K, const float* __restrict__ resid)
{
  __shared__ short As[3][128 * 32];
  __shared__ short Bs[3][128 * 32];
  const int tid  = threadIdx.x;
  const int z    = blockIdx.z;

  // bijective XCD-chunked swizzle (m204): each XCD gets a contiguous chunk
  const int nwg  = gridDim.x * gridDim.y;
  const int orig = blockIdx.y * gridDim.x + blockIdx.x;
  const int qq   = nwg >> 3, rr = nwg & 7;
  const int xcd  = orig & 7, ofs = orig >> 3;
  const int swz  = (xcd < rr ? xcd * (qq + 1) : rr * (qq + 1) + (xcd - rr) * qq) + ofs;
  const int brow = (swz / gridDim.x) * 128;
  const int bcol = (swz % gridDim.x) * 128;

  const short* Ab = A + (long)z * sA;
  const short* Bb = B + (long)z * sB;
  const float* bias = (z == 0) ? bias0 : (z == 1 ? bias1 : bias2);

  const int wave = tid >> 6, lane = tid & 63;
  const int lg = lane >> 4, lc = lane & 15;
  const int m0 = (wave >> 1) * 64, n0 = (wave & 1) * 64;

  // staging: 512 chunks of 16B per tile; thread t handles chunks t and t+256.
  // XOR seg by (row>>1)&3 (64B rows): conflict-free ds_read_b128 (r2: 9.6M->0)
  const int r0 = tid >> 2, seg = tid & 3;
  const int r1 = r0 + 64;
  const int so0 = (seg ^ ((r0 >> 1) & 3)) * 8;
  const int so1 = (seg ^ ((r1 >> 1) & 3)) * 8;
  const short* pA0 = Ab + (long)(brow + r0) * K + so0;
  const short* pA1 = Ab + (long)(brow + r1) * K + so1;
  const short* pB0 = Bb + (long)(bcol + r0) * K + so0;
  const short* pB1 = Bb + (long)(bcol + r1) * K + so1;

  f4 acc[4][4];
  f4 zero = {0.f, 0.f, 0.f, 0.f};
#pragma unroll
  for (int i = 0; i < 4; ++i)
#pragma unroll
    for (int j = 0; j < 4; ++j) acc[i][j] = zero;

  auto STAGE = [&](int buf) {
    gld16(pA0, &As[buf][tid * 8]);
    gld16(pA1, &As[buf][(tid + 256) * 8]);
    gld16(pB0, &Bs[buf][tid * 8]);
    gld16(pB1, &Bs[buf][(tid + 256) * 8]);
    pA0 += 32; pA1 += 32; pB0 += 32; pB1 += 32;
  };

  const int NT = K >> 5;
  STAGE(0);
  STAGE(1);

  for (int t = 0; t < NT; ++t) {
    const int buf = t % 3;
    if (t < NT - 1) { asm volatile("s_waitcnt vmcnt(4)" ::: "memory"); }
    else           { asm volatile("s_waitcnt vmcnt(0)" ::: "memory"); }
    __builtin_amdgcn_sched_barrier(0);
    __builtin_amdgcn_s_barrier();
    if (t + 2 < NT) STAGE((t + 2) % 3);

    const short* Al = &As[buf][0];
    const short* Bl = &Bs[buf][0];
    bf8 af[4], bfr[4];
#pragma unroll
    for (int mi = 0; mi < 4; ++mi) {
      int r = m0 + mi * 16 + lc;
      af[mi] = *(const bf8*)&Al[r * 32 + ((lg ^ ((r >> 1) & 3)) * 8)];
    }
#pragma unroll
    for (int ni = 0; ni < 4; ++ni) {
      int r = n0 + ni * 16 + lc;
      bfr[ni] = *(const bf8*)&Bl[r * 32 + ((lg ^ ((r >> 1) & 3)) * 8)];
    }
#pragma unroll
    for (int mi = 0; mi < 4; ++mi)
#pragma unroll
      for (int ni = 0; ni < 4; ++ni)
        acc[mi][ni] = __builtin_amdgcn_mfma_f32_16x16x32_bf16(af[mi], bfr[ni], acc[mi][ni], 0, 0, 0);
    __builtin_amdgcn_sched_barrier(0);   // pin compute before next iter's barrier
  }

  if (MODE == GM_RESID) {
    float* C = (float*)Cout;
#pragma unroll
    for (int ni = 0; ni < 4; ++ni) {
      int col = bcol + n0 + ni * 16 + lc;
#pragma unroll
      for (int mi = 0; mi < 4; ++mi)
#pragma unroll
        for (int r = 0; r < 4; ++r) {
          int row = brow + m0 + mi * 16 + lg * 4 + r;
          if (row < L_TOK)
            C[(long)row * N + col] = acc[mi][ni][r] + resid[(long)row * N + col];
        }
    }
  } else {
    short* C = (short*)Cout + (long)z * sC;
    const float alpha = (MODE == GM_QSCALE && z == 0) ? 0.08838834764831845f : 1.0f;
#pragma unroll
    for (int ni = 0; ni < 4; ++ni) {
      int col = bcol + n0 + ni * 16 + lc;
      float bv = bias[col];
#pragma unroll
      for (int mi = 0; mi < 4; ++mi)
#pragma unroll
        for (int r = 0; r < 4; ++r) {
          int row = brow + m0 + mi * 16 + lg * 4 + r;
          float v = acc[mi][ni][r] + bv;
          if (MODE == GM_GELU) v = 0.5f * v * (1.f + erff(v * 0.70710678118654752f));
          v *= alpha;
          C[(long)row * EDIM + col] = f2b(v);
        }
    }
  }
}

// ---------------- LayerNorm (one row per block) ----------------
__global__ __launch_bounds__(256)
void k_ln(const short* __restrict__ A, short* __restrict__ Y,
          const float* __restrict__ g0, const float* __restrict__ g1, const float* __restrict__ g2,
          const float* __restrict__ b0, const float* __restrict__ b1, const float* __restrict__ b2)
{
  const int row = blockIdx.x, z = blockIdx.y;
  const float* g = (z == 0) ? g0 : (z == 1 ? g1 : g2);
  const float* b = (z == 0) ? b0 : (z == 1 ? b1 : b2);
  const short* a = A + ((long)z * MP + row) * EDIM;
  short* y = Y + ((long)z * MP + row) * EDIM;
  const int t = threadIdx.x;
  s4v v = *(const s4v*)&a[t * 4];
  float x0 = b2f(v[0]), x1 = b2f(v[1]), x2 = b2f(v[2]), x3 = b2f(v[3]);
  float s = x0 + x1 + x2 + x3;
  float q = x0 * x0 + x1 * x1 + x2 * x2 + x3 * x3;
#pragma unroll
  for (int off = 1; off < 64; off <<= 1) { s += __shfl_xor(s, off); q += __shfl_xor(q, off); }
  __shared__ float rs[4], rq[4];
  if ((t & 63) == 0) { rs[t >> 6] = s; rq[t >> 6] = q; }
  __syncthreads();
  s = rs[0] + rs[1] + rs[2] + rs[3];
  q = rq[0] + rq[1] + rq[2] + rq[3];
  float mean = s * (1.f / 1024.f);
  float var  = q * (1.f / 1024.f) - mean * mean;
  float rstd = rsqrtf(var + 1e-5f);
  s4v o;
#pragma unroll
  for (int j = 0; j < 4; ++j) {
    int col = t * 4 + j;
    o[j] = f2b((b2f(v[j]) - mean) * rstd * g[col] + b[col]);
  }
  *(s4v*)&y[t * 4] = o;
}

// ---------------- V transpose per head: vpT[h][d][kv] ----------------
__global__ __launch_bounds__(256)
void k_vtrans(const short* __restrict__ vp, short* __restrict__ vpT)
{
  const int kb = blockIdx.x * 64, h = blockIdx.y;
  __shared__ short T[64 * 128];   // [kv][d], 16B-units XOR-swizzled by (kv&7)
  const int tid = threadIdx.x;
#pragma unroll
  for (int i = 0; i < 4; ++i) {
    int c = tid + 256 * i;
    int r = c >> 4, x = c & 15;
    bf8 val = *(const bf8*)&vp[(long)(kb + r) * EDIM + h * 128 + x * 8];
    *(bf8*)&T[r * 128 + ((x ^ (r & 7)) * 8)] = val;
  }
  __syncthreads();
#pragma unroll
  for (int i = 0; i < 4; ++i) {
    int c = tid + 256 * i;
    int dr = c >> 3, x = c & 7;
    short tmp[8];
#pragma unroll
    for (int e = 0; e < 8; ++e) {
      int kv = x * 8 + e;
      tmp[e] = T[kv * 128 + (((dr >> 3) ^ (kv & 7)) << 3) + (dr & 7)];
    }
    *(bf8*)&vpT[((long)h * 128 + dr) * MP + kb + x * 8] = *(bf8*)tmp;
  }
}

// ---------------- fused attention (no-max softmax, deferred denominator) ----
__global__ __launch_bounds__(256)
void k_attn(const short* __restrict__ qp, const short* __restrict__ kp,
            const short* __restrict__ vpT, short* __restrict__ o)
{
  const int bx = blockIdx.x;
  const int h = bx & 7, qb = (bx >> 3) * 64;   // h fastest -> one head per XCD
  const int tid = threadIdx.x, wave = tid >> 6, lane = tid & 63;
  const int lg = lane >> 4, lc = lane & 15;
  __shared__ short Ks[64 * 128];   // [kv][d] swizzled
  __shared__ short Vs[128 * 64];   // [d][kv] (V^T) swizzled
  __shared__ short Ps[4][16 * 64]; // per-wave P tile [q][kv] swizzled

  const int qrow = qb + wave * 16 + lc;
  bf8 qf[4];
#pragma unroll
  for (int d4 = 0; d4 < 4; ++d4)
    qf[d4] = *(const bf8*)&qp[(long)qrow * EDIM + h * 128 + d4 * 32 + lg * 8];

  f4 oacc[8];
  f4 zero = {0.f, 0.f, 0.f, 0.f};
#pragma unroll
  for (int dt = 0; dt < 8; ++dt) oacc[dt] = zero;
  float lsum = 0.f;

  for (int kb = 0; kb < L_TOK; kb += 64) {
#pragma unroll
    for (int i = 0; i < 4; ++i) {            // stage K tile (16KB)
      int c = tid + 256 * i; int r = c >> 4, x = c & 15;
      gld16(&kp[(long)(kb + r) * EDIM + h * 128 + (x ^ (r & 7)) * 8], &Ks[c * 8]);
    }
#pragma unroll
    for (int i = 0; i < 4; ++i) {            // stage V^T tile (16KB)
      int c = tid + 256 * i; int dr = c >> 3, x = c & 7;
      gld16(&vpT[((long)h * 128 + dr) * MP + kb + (x ^ (dr & 7)) * 8], &Vs[c * 8]);
    }
    __syncthreads();

#pragma unroll
    for (int s = 0; s < 4; ++s) {            // S^T = K·Q^T (lane owns column q)
      f4 sa = zero;
      const int krow = s * 16 + lc;
#pragma unroll
      for (int d4 = 0; d4 < 4; ++d4) {
        bf8 kf = *(const bf8*)&Ks[krow * 128 + (((d4 * 4 + lg) ^ (krow & 7)) * 8)];
        sa = __builtin_amdgcn_mfma_f32_16x16x32_bf16(kf, qf[d4], sa, 0, 0, 0);
      }
      const int kvb = kb + s * 16 + lg * 4;
      float p[4];
#pragma unroll
      for (int r = 0; r < 4; ++r) {
        float e = __expf(sa[r]);
        p[r] = (kvb + r < L_TOK) ? e : 0.f;
        lsum += p[r];
      }
      s4v pk; pk[0] = f2b(p[0]); pk[1] = f2b(p[1]); pk[2] = f2b(p[2]); pk[3] = f2b(p[3]);
      *(s4v*)&Ps[wave][lc * 64 + ((s * 16 + lg * 4) ^ ((lc & 7) << 3))] = pk;
    }
    bf8 pf0 = *(const bf8*)&Ps[wave][lc * 64 + ((lg * 8) ^ ((lc & 7) << 3))];
    bf8 pf1 = *(const bf8*)&Ps[wave][lc * 64 + ((32 + lg * 8) ^ ((lc & 7) << 3))];
#pragma unroll
    for (int dt = 0; dt < 8; ++dt) {         // O += P·V
      const int vrow = dt * 16 + lc;
      bf8 vf0 = *(const bf8*)&Vs[vrow * 64 + ((lg ^ (vrow & 7)) * 8)];
      bf8 vf1 = *(const bf8*)&Vs[vrow * 64 + (((4 + lg) ^ (vrow & 7)) * 8)];
      oacc[dt] = __builtin_amdgcn_mfma_f32_16x16x32_bf16(pf0, vf0, oacc[dt], 0, 0, 0);
      oacc[dt] = __builtin_amdgcn_mfma_f32_16x16x32_bf16(pf1, vf1, oacc[dt], 0, 0, 0);
    }
    __syncthreads();
  }

  lsum += __shfl_xor(lsum, 16);              // combine the 4 lane-groups
  lsum += __shfl_xor(lsum, 32);
  float rinv[4];
#pragma unroll
  for (int r = 0; r < 4; ++r) rinv[r] = 1.f / __shfl(lsum, lg * 4 + r);
#pragma unroll
  for (int dt = 0; dt < 8; ++dt)
#pragma unroll
    for (int r = 0; r < 4; ++r) {
      int orow = qb + wave * 16 + lg * 4 + r;
      o[(long)orow * EDIM + h * 128 + dt * 16 + lc] = f2b(oacc[dt][r] * rinv[r]);
    }
}

// ---------------- launch ----------------
extern "C" void kernel_launch(void* const* d_in, const int* in_sizes, int n_in,
                              void* d_out, int out_size, void* d_ws, size_t ws_size,
                              hipStream_t stream)
{
  const float* x   = (const float*)d_in[0];
  const float* ipb = (const float*)d_in[20];
  const float* opb = (const float*)d_in[22];

  char* ws = (char*)d_ws;
  short* regA = (short*)(ws + 0);                  // 25,657,344 B : xb -> aln -> proj
  short* regB = (short*)(ws + 25657344);           // 22,806,528 B : h1 -> lnq -> {o, o2}
  short* w1b  = (short*)(ws + 48463872);
  short* w2b  = (short*)(ws + 69697536);
  short* wpb  = (short*)(ws + 75988992);
  short* wob  = (short*)(ws + 82280448);
  short* wtb  = (short*)(ws + 84377600);
  short* vpT  = (short*)(ws + 91455488);           // end 99,057,664

  short* xb  = regA;
  short* h1  = regB;
  short* aln = regA;
  short* lnq = regB;
  short* proj = regA;
  short* ob  = regB;
  short* o2  = (short*)(ws + 25657344 + 7602176);

  // bf16 conversions
  k_cvt_pad<<<12528, 256, 0, stream>>>(x, xb, 3149280, 3207168);
  k_cvt<<<3456, 256, 0, stream>>>((const float*)d_in[1],  w1b,            884736);
  k_cvt<<<3456, 256, 0, stream>>>((const float*)d_in[7],  w1b + 3538944,  884736);
  k_cvt<<<3456, 256, 0, stream>>>((const float*)d_in[13], w1b + 7077888,  884736);
  k_cvt<<<1024, 256, 0, stream>>>((const float*)d_in[3],  w2b,            262144);
  k_cvt<<<1024, 256, 0, stream>>>((const float*)d_in[9],  w2b + 1048576,  262144);
  k_cvt<<<1024, 256, 0, stream>>>((const float*)d_in[15], w2b + 2097152,  262144);
  k_cvt<<<3072, 256, 0, stream>>>((const float*)d_in[19], wpb,            786432);
  k_cvt<<<1024, 256, 0, stream>>>((const float*)d_in[21], wob,            262144);
  k_cvt<<<3456, 256, 0, stream>>>((const float*)d_in[23], wtb,            884736);

  dim3 g3(8, 29, 3), g1(8, 29, 1);
  // MLP first linear + GELU
  k_gemm<GM_GELU><<<g3, 256, 0, stream>>>(xb, 0, w1b, 3538944,
      (const float*)d_in[2], (const float*)d_in[8], (const float*)d_in[14],
      h1, (long)MP * EDIM, EDIM, DIMV, nullptr);
  // MLP second linear + bias
  k_gemm<GM_BIAS><<<g3, 256, 0, stream>>>(h1, (long)MP * EDIM, w2b, 1048576,
      (const float*)d_in[4], (const float*)d_in[10], (const float*)d_in[16],
      aln, (long)MP * EDIM, EDIM, EDIM, nullptr);
  // LayerNorm
  dim3 gl(MP, 3);
  k_ln<<<gl, 256, 0, stream>>>(aln, lnq,
      (const float*)d_in[5], (const float*)d_in[11], (const float*)d_in[17],
      (const float*)d_in[6], (const float*)d_in[12], (const float*)d_in[18]);
  // in_proj (q scaled by 1/sqrt(D))
  k_gemm<GM_QSCALE><<<g3, 256, 0, stream>>>(lnq, (long)MP * EDIM, wpb, 1048576,
      ipb, ipb + 1024, ipb + 2048,
      proj, (long)MP * EDIM, EDIM, EDIM, nullptr);
  // V transpose per head
  dim3 gt(MP / 64, 8);
  k_vtrans<<<gt, 256, 0, stream>>>(proj + 2L * MP * EDIM, vpT);
  // attention
  k_attn<<<(MP / 64) * 8, 256, 0, stream>>>(proj, proj + (long)MP * EDIM, vpT, ob);
  // out_proj
  k_gemm<GM_BIAS><<<g1, 256, 0, stream>>>(ob, 0, wob, 0,
      opb, opb, opb, o2, 0, EDIM, EDIM, nullptr);
  // to_out + residual (fp32 out)
  dim3 g5(27, 29, 1);
  k_gemm<GM_RESID><<<g5, 256, 0, stream>>>(o2, 0, wtb, 0,
      nullptr, nullptr, nullptr, d_out, 0, DIMV, EDIM, x);
}

// Round 4
// 417.798 us; speedup vs baseline: 1.1726x; 1.0643x over previous
//
#include <hip/hip_runtime.h>
#include <hip/hip_bf16.h>

#define L_TOK 3645
#define MP    3712
#define DIMV  3456
#define EDIM  1024

typedef __attribute__((ext_vector_type(8))) short bf8;   // 8 bf16 in 4 VGPRs
typedef __attribute__((ext_vector_type(4))) short s4v;   // 4 bf16
typedef __attribute__((ext_vector_type(4))) float f4;    // MFMA accumulator

__device__ __forceinline__ short f2b(float f) {          // fp32 -> bf16 RNE
  union { float f; unsigned u; } v; v.f = f;
  unsigned r = v.u + 0x7fffu + ((v.u >> 16) & 1u);
  return (short)(r >> 16);
}
__device__ __forceinline__ float b2f(short s) {
  union { unsigned u; float f; } v; v.u = ((unsigned)(unsigned short)s) << 16;
  return v.f;
}
__device__ __forceinline__ void gld16(const void* g, void* l) {
  __builtin_amdgcn_global_load_lds(
      (const __attribute__((address_space(1))) void*)(unsigned long long)g,
      (__attribute__((address_space(3))) void*)(unsigned)(unsigned long long)l,
      16, 0, 0);
}

// ---------------- converts ----------------
__global__ __launch_bounds__(256) void k_cvt(const float* __restrict__ src,
                                             short* __restrict__ dst, int n4) {
  int i = blockIdx.x * 256 + threadIdx.x;
  if (i >= n4) return;
  float4 v = ((const float4*)src)[i];
  s4v o; o[0] = f2b(v.x); o[1] = f2b(v.y); o[2] = f2b(v.z); o[3] = f2b(v.w);
  ((s4v*)dst)[i] = o;
}
__global__ __launch_bounds__(256) void k_cvt_pad(const float* __restrict__ src,
                                                 short* __restrict__ dst, int n4src, int n4tot) {
  int i = blockIdx.x * 256 + threadIdx.x;
  if (i >= n4tot) return;
  s4v o; o[0] = 0; o[1] = 0; o[2] = 0; o[3] = 0;
  if (i < n4src) {
    float4 v = ((const float4*)src)[i];
    o[0] = f2b(v.x); o[1] = f2b(v.y); o[2] = f2b(v.z); o[3] = f2b(v.w);
  }
  ((s4v*)dst)[i] = o;
}

// ---------------- GEMM (NT: C[m][n] = sum_k A[m][k]*B[n][k]) ----------------
// Triple-buffered LDS, counted vmcnt (never 0 until the last tile), single
// barrier per K-step. Tile t staged 2 iterations ahead of consumption.
#define GM_GELU   0
#define GM_BIAS   1
#define GM_QSCALE 2
#define GM_RESID  3

template<int MODE>
__global__ __launch_bounds__(256)
void k_gemm(const short* __restrict__ A, long sA,
            const short* __restrict__ B, long sB,
            const float* __restrict__ bias0, const float* __restrict__ bias1,
            const float* __restrict__ bias2,
            void* __restrict__ Cout, long sC,
            int N, int K, const float* __restrict__ resid)
{
  __shared__ short As[3][128 * 32];
  __shared__ short Bs[3][128 * 32];
  const int tid  = threadIdx.x;
  const int z    = blockIdx.z;

  // bijective XCD-chunked swizzle (m204): each XCD gets a contiguous chunk
  const int nwg  = gridDim.x * gridDim.y;
  const int orig = blockIdx.y * gridDim.x + blockIdx.x;
  const int qq   = nwg >> 3, rr = nwg & 7;
  const int xcd  = orig & 7, ofs = orig >> 3;
  const int swz  = (xcd < rr ? xcd * (qq + 1) : rr * (qq + 1) + (xcd - rr) * qq) + ofs;
  const int brow = (swz / gridDim.x) * 128;
  const int bcol = (swz % gridDim.x) * 128;

  const short* Ab = A + (long)z * sA;
  const short* Bb = B + (long)z * sB;
  const float* bias = (z == 0) ? bias0 : (z == 1 ? bias1 : bias2);

  const int wave = tid >> 6, lane = tid & 63;
  const int lg = lane >> 4, lc = lane & 15;
  const int m0 = (wave >> 1) * 64, n0 = (wave & 1) * 64;

  // staging: 512 chunks of 16B per tile; thread t handles chunks t and t+256.
  // XOR seg by (row>>1)&3 (64B rows): conflict-free ds_read_b128 (r2: 9.6M->0)
  const int r0 = tid >> 2, seg = tid & 3;
  const int r1 = r0 + 64;
  const int so0 = (seg ^ ((r0 >> 1) & 3)) * 8;
  const int so1 = (seg ^ ((r1 >> 1) & 3)) * 8;
  const short* pA0 = Ab + (long)(brow + r0) * K + so0;
  const short* pA1 = Ab + (long)(brow + r1) * K + so1;
  const short* pB0 = Bb + (long)(bcol + r0) * K + so0;
  const short* pB1 = Bb + (long)(bcol + r1) * K + so1;

  f4 acc[4][4];
  f4 zero = {0.f, 0.f, 0.f, 0.f};
#pragma unroll
  for (int i = 0; i < 4; ++i)
#pragma unroll
    for (int j = 0; j < 4; ++j) acc[i][j] = zero;

  auto STAGE = [&](int buf) {
    gld16(pA0, &As[buf][tid * 8]);
    gld16(pA1, &As[buf][(tid + 256) * 8]);
    gld16(pB0, &Bs[buf][tid * 8]);
    gld16(pB1, &Bs[buf][(tid + 256) * 8]);
    pA0 += 32; pA1 += 32; pB0 += 32; pB1 += 32;
  };

  const int NT = K >> 5;
  STAGE(0);
  STAGE(1);

  for (int t = 0; t < NT; ++t) {
    const int buf = t % 3;
    if (t < NT - 1) { asm volatile("s_waitcnt vmcnt(4)" ::: "memory"); }
    else           { asm volatile("s_waitcnt vmcnt(0)" ::: "memory"); }
    __builtin_amdgcn_sched_barrier(0);
    __builtin_amdgcn_s_barrier();
    if (t + 2 < NT) STAGE((t + 2) % 3);

    const short* Al = &As[buf][0];
    const short* Bl = &Bs[buf][0];
    bf8 af[4], bfr[4];
#pragma unroll
    for (int mi = 0; mi < 4; ++mi) {
      int r = m0 + mi * 16 + lc;
      af[mi] = *(const bf8*)&Al[r * 32 + ((lg ^ ((r >> 1) & 3)) * 8)];
    }
#pragma unroll
    for (int ni = 0; ni < 4; ++ni) {
      int r = n0 + ni * 16 + lc;
      bfr[ni] = *(const bf8*)&Bl[r * 32 + ((lg ^ ((r >> 1) & 3)) * 8)];
    }
    __builtin_amdgcn_s_setprio(1);
#pragma unroll
    for (int mi = 0; mi < 4; ++mi)
#pragma unroll
      for (int ni = 0; ni < 4; ++ni)
        acc[mi][ni] = __builtin_amdgcn_mfma_f32_16x16x32_bf16(af[mi], bfr[ni], acc[mi][ni], 0, 0, 0);
    __builtin_amdgcn_s_setprio(0);
    __builtin_amdgcn_sched_barrier(0);   // pin compute before next iter's barrier
  }

  if (MODE == GM_RESID) {
    float* C = (float*)Cout;
#pragma unroll
    for (int ni = 0; ni < 4; ++ni) {
      int col = bcol + n0 + ni * 16 + lc;
#pragma unroll
      for (int mi = 0; mi < 4; ++mi)
#pragma unroll
        for (int r = 0; r < 4; ++r) {
          int row = brow + m0 + mi * 16 + lg * 4 + r;
          if (row < L_TOK)
            C[(long)row * N + col] = acc[mi][ni][r] + resid[(long)row * N + col];
        }
    }
  } else {
    short* C = (short*)Cout + (long)z * sC;
    const float alpha = (MODE == GM_QSCALE && z == 0) ? 0.08838834764831845f : 1.0f;
#pragma unroll
    for (int ni = 0; ni < 4; ++ni) {
      int col = bcol + n0 + ni * 16 + lc;
      float bv = bias[col];
#pragma unroll
      for (int mi = 0; mi < 4; ++mi)
#pragma unroll
        for (int r = 0; r < 4; ++r) {
          int row = brow + m0 + mi * 16 + lg * 4 + r;
          float v = acc[mi][ni][r] + bv;
          if (MODE == GM_GELU) v = 0.5f * v * (1.f + erff(v * 0.70710678118654752f));
          v *= alpha;
          C[(long)row * EDIM + col] = f2b(v);
        }
    }
  }
}

// ---------------- LayerNorm (one row per block) ----------------
__global__ __launch_bounds__(256)
void k_ln(const short* __restrict__ A, short* __restrict__ Y,
          const float* __restrict__ g0, const float* __restrict__ g1, const float* __restrict__ g2,
          const float* __restrict__ b0, const float* __restrict__ b1, const float* __restrict__ b2)
{
  const int row = blockIdx.x, z = blockIdx.y;
  const float* g = (z == 0) ? g0 : (z == 1 ? g1 : g2);
  const float* b = (z == 0) ? b0 : (z == 1 ? b1 : b2);
  const short* a = A + ((long)z * MP + row) * EDIM;
  short* y = Y + ((long)z * MP + row) * EDIM;
  const int t = threadIdx.x;
  s4v v = *(const s4v*)&a[t * 4];
  float x0 = b2f(v[0]), x1 = b2f(v[1]), x2 = b2f(v[2]), x3 = b2f(v[3]);
  float s = x0 + x1 + x2 + x3;
  float q = x0 * x0 + x1 * x1 + x2 * x2 + x3 * x3;
#pragma unroll
  for (int off = 1; off < 64; off <<= 1) { s += __shfl_xor(s, off); q += __shfl_xor(q, off); }
  __shared__ float rs[4], rq[4];
  if ((t & 63) == 0) { rs[t >> 6] = s; rq[t >> 6] = q; }
  __syncthreads();
  s = rs[0] + rs[1] + rs[2] + rs[3];
  q = rq[0] + rq[1] + rq[2] + rq[3];
  float mean = s * (1.f / 1024.f);
  float var  = q * (1.f / 1024.f) - mean * mean;
  float rstd = rsqrtf(var + 1e-5f);
  s4v o;
#pragma unroll
  for (int j = 0; j < 4; ++j) {
    int col = t * 4 + j;
    o[j] = f2b((b2f(v[j]) - mean) * rstd * g[col] + b[col]);
  }
  *(s4v*)&y[t * 4] = o;
}

// ---------------- V transpose per head: vpT[h][d][kv] ----------------
__global__ __launch_bounds__(256)
void k_vtrans(const short* __restrict__ vp, short* __restrict__ vpT)
{
  const int kb = blockIdx.x * 64, h = blockIdx.y;
  __shared__ short T[64 * 128];   // [kv][d], 16B-units XOR-swizzled by (kv&7)
  const int tid = threadIdx.x;
#pragma unroll
  for (int i = 0; i < 4; ++i) {
    int c = tid + 256 * i;
    int r = c >> 4, x = c & 15;
    bf8 val = *(const bf8*)&vp[(long)(kb + r) * EDIM + h * 128 + x * 8];
    *(bf8*)&T[r * 128 + ((x ^ (r & 7)) * 8)] = val;
  }
  __syncthreads();
#pragma unroll
  for (int i = 0; i < 4; ++i) {
    int c = tid + 256 * i;
    int dr = c >> 3, x = c & 7;
    short tmp[8];
#pragma unroll
    for (int e = 0; e < 8; ++e) {
      int kv = x * 8 + e;
      tmp[e] = T[kv * 128 + (((dr >> 3) ^ (kv & 7)) << 3) + (dr & 7)];
    }
    *(bf8*)&vpT[((long)h * 128 + dr) * MP + kb + x * 8] = *(bf8*)tmp;
  }
}

// ---------------- fused attention (no-max softmax, deferred denominator) ----
// Double-buffered K/V, counted vmcnt(8): tile t+1's loads stay in flight
// across the whole QK+softmax+PV phase of tile t. Two barriers per tile.
__global__ __launch_bounds__(256)
void k_attn(const short* __restrict__ qp, const short* __restrict__ kp,
            const short* __restrict__ vpT, short* __restrict__ o)
{
  const int bx = blockIdx.x;
  const int h = bx & 7, qb = (bx >> 3) * 64;   // h fastest -> one head per XCD
  const int tid = threadIdx.x, wave = tid >> 6, lane = tid & 63;
  const int lg = lane >> 4, lc = lane & 15;
  __shared__ short Ks[2][64 * 128];   // [kv][d] swizzled, double-buffered
  __shared__ short Vs[2][128 * 64];   // [d][kv] (V^T) swizzled, double-buffered
  __shared__ short Ps[4][16 * 64];    // per-wave P tile [q][kv] swizzled

  const int qrow = qb + wave * 16 + lc;
  bf8 qf[4];
#pragma unroll
  for (int d4 = 0; d4 < 4; ++d4)
    qf[d4] = *(const bf8*)&qp[(long)qrow * EDIM + h * 128 + d4 * 32 + lg * 8];

  f4 oacc[8];
  f4 zero = {0.f, 0.f, 0.f, 0.f};
#pragma unroll
  for (int dt = 0; dt < 8; ++dt) oacc[dt] = zero;
  float lsum = 0.f;

  auto STAGE = [&](short* ksb, short* vsb, int kb) {
#pragma unroll
    for (int i = 0; i < 4; ++i) {            // K tile (16KB)
      int c = tid + 256 * i; int r = c >> 4, x = c & 15;
      gld16(&kp[(long)(kb + r) * EDIM + h * 128 + (x ^ (r & 7)) * 8], &ksb[c * 8]);
    }
#pragma unroll
    for (int i = 0; i < 4; ++i) {            // V^T tile (16KB)
      int c = tid + 256 * i; int dr = c >> 3, x = c & 7;
      gld16(&vpT[((long)h * 128 + dr) * MP + kb + (x ^ (dr & 7)) * 8], &vsb[c * 8]);
    }
  };

  const int NTILE = (L_TOK + 63) / 64;       // 57
  STAGE(Ks[0], Vs[0], 0);

  for (int t = 0; t < NTILE; ++t) {
    const int kb = t * 64;
    const short* ksb = Ks[t & 1];
    const short* vsb = Vs[t & 1];
    __builtin_amdgcn_s_barrier();            // prev compute done in all waves
    if (t + 1 < NTILE) {
      STAGE(Ks[(t + 1) & 1], Vs[(t + 1) & 1], kb + 64);
      asm volatile("s_waitcnt vmcnt(8)" ::: "memory");   // drain tile t only
    } else {
      asm volatile("s_waitcnt vmcnt(0)" ::: "memory");
    }
    __builtin_amdgcn_sched_barrier(0);
    __builtin_amdgcn_s_barrier();            // tile t visible to all waves
    __builtin_amdgcn_sched_barrier(0);

#pragma unroll
    for (int s = 0; s < 4; ++s) {            // S^T = K·Q^T (lane owns column q)
      f4 sa = zero;
      const int krow = s * 16 + lc;
      bf8 kf[4];
#pragma unroll
      for (int d4 = 0; d4 < 4; ++d4)
        kf[d4] = *(const bf8*)&ksb[krow * 128 + (((d4 * 4 + lg) ^ (krow & 7)) * 8)];
      __builtin_amdgcn_s_setprio(1);
#pragma unroll
      for (int d4 = 0; d4 < 4; ++d4)
        sa = __builtin_amdgcn_mfma_f32_16x16x32_bf16(kf[d4], qf[d4], sa, 0, 0, 0);
      __builtin_amdgcn_s_setprio(0);
      const int kvb = kb + s * 16 + lg * 4;
      float p[4];
#pragma unroll
      for (int r = 0; r < 4; ++r) {
        float e = __expf(sa[r]);
        p[r] = (kvb + r < L_TOK) ? e : 0.f;
        lsum += p[r];
      }
      s4v pk; pk[0] = f2b(p[0]); pk[1] = f2b(p[1]); pk[2] = f2b(p[2]); pk[3] = f2b(p[3]);
      *(s4v*)&Ps[wave][lc * 64 + ((s * 16 + lg * 4) ^ ((lc & 7) << 3))] = pk;
    }
    bf8 pf0 = *(const bf8*)&Ps[wave][lc * 64 + ((lg * 8) ^ ((lc & 7) << 3))];
    bf8 pf1 = *(const bf8*)&Ps[wave][lc * 64 + ((32 + lg * 8) ^ ((lc & 7) << 3))];
#pragma unroll
    for (int dt = 0; dt < 8; ++dt) {         // O += P·V
      const int vrow = dt * 16 + lc;
      bf8 vf0 = *(const bf8*)&vsb[vrow * 64 + ((lg ^ (vrow & 7)) * 8)];
      bf8 vf1 = *(const bf8*)&vsb[vrow * 64 + (((4 + lg) ^ (vrow & 7)) * 8)];
      __builtin_amdgcn_s_setprio(1);
      oacc[dt] = __builtin_amdgcn_mfma_f32_16x16x32_bf16(pf0, vf0, oacc[dt], 0, 0, 0);
      oacc[dt] = __builtin_amdgcn_mfma_f32_16x16x32_bf16(pf1, vf1, oacc[dt], 0, 0, 0);
      __builtin_amdgcn_s_setprio(0);
    }
    __builtin_amdgcn_sched_barrier(0);
  }

  lsum += __shfl_xor(lsum, 16);              // combine the 4 lane-groups
  lsum += __shfl_xor(lsum, 32);
  float rinv[4];
#pragma unroll
  for (int r = 0; r < 4; ++r) rinv[r] = 1.f / __shfl(lsum, lg * 4 + r);
#pragma unroll
  for (int dt = 0; dt < 8; ++dt)
#pragma unroll
    for (int r = 0; r < 4; ++r) {
      int orow = qb + wave * 16 + lg * 4 + r;
      o[(long)orow * EDIM + h * 128 + dt * 16 + lc] = f2b(oacc[dt][r] * rinv[r]);
    }
}

// ---------------- launch ----------------
extern "C" void kernel_launch(void* const* d_in, const int* in_sizes, int n_in,
                              void* d_out, int out_size, void* d_ws, size_t ws_size,
                              hipStream_t stream)
{
  const float* x   = (const float*)d_in[0];
  const float* ipb = (const float*)d_in[20];
  const float* opb = (const float*)d_in[22];

  char* ws = (char*)d_ws;
  short* regA = (short*)(ws + 0);                  // 25,657,344 B : xb -> aln -> proj
  short* regB = (short*)(ws + 25657344);           // 22,806,528 B : h1 -> lnq -> {o, o2}
  short* w1b  = (short*)(ws + 48463872);
  short* w2b  = (short*)(ws + 69697536);
  short* wpb  = (short*)(ws + 75988992);
  short* wob  = (short*)(ws + 82280448);
  short* wtb  = (short*)(ws + 84377600);
  short* vpT  = (short*)(ws + 91455488);           // end 99,057,664

  short* xb  = regA;
  short* h1  = regB;
  short* aln = regA;
  short* lnq = regB;
  short* proj = regA;
  short* ob  = regB;
  short* o2  = (short*)(ws + 25657344 + 7602176);

  // bf16 conversions
  k_cvt_pad<<<12528, 256, 0, stream>>>(x, xb, 3149280, 3207168);
  k_cvt<<<3456, 256, 0, stream>>>((const float*)d_in[1],  w1b,            884736);
  k_cvt<<<3456, 256, 0, stream>>>((const float*)d_in[7],  w1b + 3538944,  884736);
  k_cvt<<<3456, 256, 0, stream>>>((const float*)d_in[13], w1b + 7077888,  884736);
  k_cvt<<<1024, 256, 0, stream>>>((const float*)d_in[3],  w2b,            262144);
  k_cvt<<<1024, 256, 0, stream>>>((const float*)d_in[9],  w2b + 1048576,  262144);
  k_cvt<<<1024, 256, 0, stream>>>((const float*)d_in[15], w2b + 2097152,  262144);
  k_cvt<<<3072, 256, 0, stream>>>((const float*)d_in[19], wpb,            786432);
  k_cvt<<<1024, 256, 0, stream>>>((const float*)d_in[21], wob,            262144);
  k_cvt<<<3456, 256, 0, stream>>>((const float*)d_in[23], wtb,            884736);

  dim3 g3(8, 29, 3), g1(8, 29, 1);
  // MLP first linear + GELU
  k_gemm<GM_GELU><<<g3, 256, 0, stream>>>(xb, 0, w1b, 3538944,
      (const float*)d_in[2], (const float*)d_in[8], (const float*)d_in[14],
      h1, (long)MP * EDIM, EDIM, DIMV, nullptr);
  // MLP second linear + bias
  k_gemm<GM_BIAS><<<g3, 256, 0, stream>>>(h1, (long)MP * EDIM, w2b, 1048576,
      (const float*)d_in[4], (const float*)d_in[10], (const float*)d_in[16],
      aln, (long)MP * EDIM, EDIM, EDIM, nullptr);
  // LayerNorm
  dim3 gl(MP, 3);
  k_ln<<<gl, 256, 0, stream>>>(aln, lnq,
      (const float*)d_in[5], (const float*)d_in[11], (const float*)d_in[17],
      (const float*)d_in[6], (const float*)d_in[12], (const float*)d_in[18]);
  // in_proj (q scaled by 1/sqrt(D))
  k_gemm<GM_QSCALE><<<g3, 256, 0, stream>>>(lnq, (long)MP * EDIM, wpb, 1048576,
      ipb, ipb + 1024, ipb + 2048,
      proj, (long)MP * EDIM, EDIM, EDIM, nullptr);
  // V transpose per head
  dim3 gt(MP / 64, 8);
  k_vtrans<<<gt, 256, 0, stream>>>(proj + 2L * MP * EDIM, vpT);
  // attention
  k_attn<<<(MP / 64) * 8, 256, 0, stream>>>(proj, proj + (long)MP * EDIM, vpT, ob);
  // out_proj
  k_gemm<GM_BIAS><<<g1, 256, 0, stream>>>(ob, 0, wob, 0,
      opb, opb, opb, o2, 0, EDIM, EDIM, nullptr);
  // to_out + residual (fp32 out)
  dim3 g5(27, 29, 1);
  k_gemm<GM_RESID><<<g5, 256, 0, stream>>>(o2, 0, wtb, 0,
      nullptr, nullptr, nullptr, d_out, 0, DIMV, EDIM, x);
}